// Round 3
// baseline (24904.291 us; speedup 1.0000x reference)
//
#include <hip/hip_runtime.h>
#include <stddef.h>

#define T_STEPS 512
#define WROWS 16
#define WPITCH 1028   // padded row pitch (floats) for W tile: 1024 + 4
#define XPITCH 132    // padded row pitch (floats) for x/h staging: 128 + 4

typedef unsigned int u32;

__device__ __forceinline__ float sigmoidf_(float x) {
    return 1.0f / (1.0f + __expf(-x));
}
__device__ __forceinline__ float tanhf_(float x) {
    float ax = fabsf(x);
    float e = __expf(-2.0f * ax);
    float t = (1.0f - e) / (1.0f + e);
    return copysignf(t, x);
}

// agent-scope (device-coherent) 4-float load: bypasses non-coherent per-XCD caches
__device__ __forceinline__ float4 ld_coh4(const float* p) {
    float4 v;
    v.x = __hip_atomic_load(p + 0, __ATOMIC_RELAXED, __HIP_MEMORY_SCOPE_AGENT);
    v.y = __hip_atomic_load(p + 1, __ATOMIC_RELAXED, __HIP_MEMORY_SCOPE_AGENT);
    v.z = __hip_atomic_load(p + 2, __ATOMIC_RELAXED, __HIP_MEMORY_SCOPE_AGENT);
    v.w = __hip_atomic_load(p + 3, __ATOMIC_RELAXED, __HIP_MEMORY_SCOPE_AGENT);
    return v;
}

__device__ __forceinline__ void waitflag(u32* c) {
    if (threadIdx.x == 0) {
        while (__hip_atomic_load(c, __ATOMIC_ACQUIRE, __HIP_MEMORY_SCOPE_AGENT) < 128u)
            __builtin_amdgcn_s_sleep(2);
    }
    __builtin_amdgcn_fence(__ATOMIC_ACQUIRE, "agent");
    __syncthreads();
}

// One 4-chunk phase (512 k-values): stage [16 b-rows][128 k] into LDS (prefetching the
// next chunk into registers while computing the current one), accumulate dot-products.
template <bool COH>
__device__ __forceinline__ void run_phase(
    const float* __restrict__ src, size_t bstride, int kbase,
    const float (*Wl)[WPITCH], float (*xh)[XPITCH],
    int tid, int slot, int pb, float4& accv)
{
    const int f0 = tid;
    const int f1 = 256 + tid;
    const int r0 = f0 >> 5, c0 = (f0 & 31) << 2;
    const int r1 = f1 >> 5, c1 = (f1 & 31) << 2;
    const float* p0 = src + (size_t)r0 * bstride + c0;
    const float* p1 = src + (size_t)r1 * bstride + c1;
    float4 A = COH ? ld_coh4(p0) : *(const float4*)p0;
    float4 B = COH ? ld_coh4(p1) : *(const float4*)p1;
#pragma unroll 1
    for (int ch = 0; ch < 4; ++ch) {
        __syncthreads();                 // previous chunk's consumers done with xh
        *(float4*)&xh[r0][c0] = A;
        *(float4*)&xh[r1][c1] = B;
        __syncthreads();
        if (ch < 3) {                    // prefetch next chunk while computing this one
            const float* q0 = p0 + ((ch + 1) << 7);
            const float* q1 = p1 + ((ch + 1) << 7);
            A = COH ? ld_coh4(q0) : *(const float4*)q0;
            B = COH ? ld_coh4(q1) : *(const float4*)q1;
        }
        const float* wrow = &Wl[slot][kbase + (ch << 7)];
        const float* xrow = &xh[pb][0];
#pragma unroll
        for (int kk = 0; kk < 128; kk += 4) {
            float4 w = *(const float4*)(wrow + kk);
            float4 x = *(const float4*)(xrow + kk);
            accv.x = fmaf(w.x, x.x, accv.x);
            accv.y = fmaf(w.y, x.y, accv.y);
            accv.z = fmaf(w.z, x.z, accv.z);
            accv.w = fmaf(w.w, x.w, accv.w);
        }
    }
}

// 512 blocks x 256 threads. Co-residency is guaranteed WITHOUT cooperative launch:
// LDS 75264 B/block -> exactly 2 blocks/CU; launch_bounds(256,2) caps VGPR<=256 so
// 8 waves/CU fit; grid = 512 = 2 * 256 CUs -> every block is resident -> flag-based
// producer/consumer sync cannot deadlock.
// bid < 256: layer 0; bid >= 256: layer 1.
// Per layer: bg in {0,1} covers 16 batch rows; hg in [0,128) covers 4 hidden units.
// Thread (p,g): p=tid>>2 -> (pb=p&15 batch, ph=p>>4 hidden), g=tid&3 gate (i,f,g,o).
// Gate row j = g*512 + hg*4 + ph; K = 1024 = [W_ih row | W_hh row], staged once in LDS.
__global__ void __launch_bounds__(256, 2)
lstm_pipe(const float* __restrict__ inp,                     // [B][T][D]
          const float* __restrict__ Wih0, const float* __restrict__ Whh0,
          const float* __restrict__ bih0, const float* __restrict__ bhh0,
          const float* __restrict__ Wih1, const float* __restrict__ Whh1,
          const float* __restrict__ bih1, const float* __restrict__ bhh1,
          float* __restrict__ out,                           // [B][T][H]
          float* __restrict__ h0seq,                         // [T][B][H] (workspace)
          u32* __restrict__ cnt)                             // [2][2][512] flags
{
    __shared__ float Wl[WROWS][WPITCH];   // 65792 B
    __shared__ float xh[16][XPITCH];      //  8448 B
    __shared__ float gl[64][4];           //  1024 B

    const int tid = threadIdx.x;
    const int bid = blockIdx.x;
    const int layer = bid >> 8;
    const int lb = bid & 255;
    const int bg = lb >> 7;
    const int hg = lb & 127;

    const int g = tid & 3;
    const int p = tid >> 2;
    const int pb = p & 15;
    const int ph = p >> 4;
    const int hh = (hg << 2) + ph;
    const int j = (g << 9) + hh;
    const int slot = (ph << 2) + g;

    const float* Wih = layer ? Wih1 : Wih0;
    const float* Whh = layer ? Whh1 : Whh0;
    const float* bih = layer ? bih1 : bih0;
    const float* bhh = layer ? bhh1 : bhh0;

    // ---- stage W (concat [W_ih | W_hh] rows) into LDS once ----
    for (int r = 0; r < WROWS; ++r) {
        const int g_r = r & 3, ph_r = r >> 2;
        const int j_r = (g_r << 9) + (hg << 2) + ph_r;
        const int col = tid << 2;
        float4 v;
        if (col < 512) v = *(const float4*)(Wih + (size_t)j_r * 512 + col);
        else           v = *(const float4*)(Whh + (size_t)j_r * 512 + (col - 512));
        *(float4*)&Wl[r][col] = v;
    }
    const float bias = bih[j] + bhh[j];

    // update-thread mapping (tid < 64): q -> (pb_u = q>>2, ph_u = q&3)
    const int q = tid;
    const int pb_u = q >> 2, ph_u = q & 3;
    const int pprime = (ph_u << 4) + pb_u;
    const int b_u = (bg << 4) + pb_u;
    const int hh_u = (hg << 2) + ph_u;
    float c_reg = 0.0f;

    const int cidx_own = ((layer << 1) + bg) << 9;  // + t
    const int cidx_l0  = bg << 9;                   // layer0 flags, same bg

    __syncthreads();

    for (int t = 0; t < T_STEPS; ++t) {
        float4 accv = make_float4(0.f, 0.f, 0.f, 0.f);
        if (layer == 0) {
            // x-part: raw input, no dependency
            run_phase<false>(inp + ((size_t)(bg * 16) * 512 + t) * 512,
                             (size_t)512 * 512, 0, Wl, xh, tid, slot, pb, accv);
            if (t > 0) {  // h-part: own layer, step t-1
                waitflag(&cnt[cidx_own + t - 1]);
                run_phase<true>(h0seq + ((size_t)(t - 1) * 32 + bg * 16) * 512,
                                512, 512, Wl, xh, tid, slot, pb, accv);
            }
        } else {
            // x-part: layer0 output at step t (cross-layer pipeline coupling)
            waitflag(&cnt[cidx_l0 + t]);
            run_phase<true>(h0seq + ((size_t)t * 32 + bg * 16) * 512,
                            512, 0, Wl, xh, tid, slot, pb, accv);
            if (t > 0) {  // h-part: own layer hidden state, read back from d_out
                waitflag(&cnt[cidx_own + t - 1]);
                run_phase<true>(out + ((size_t)(bg * 16) * 512 + (t - 1)) * 512,
                                (size_t)512 * 512, 512, Wl, xh, tid, slot, pb, accv);
            }
        }
        gl[p][g] = (accv.x + accv.y) + (accv.z + accv.w) + bias;
        __syncthreads();
        if (tid < 64) {  // wave 0: LSTM cell update for this block's 64 (b,h) pairs
            const float4 gv = *(const float4*)&gl[pprime][0];
            const float i_ = sigmoidf_(gv.x);
            const float f_ = sigmoidf_(gv.y);
            const float g_ = tanhf_(gv.z);
            const float o_ = sigmoidf_(gv.w);
            c_reg = f_ * c_reg + i_ * g_;
            const float hv = o_ * tanhf_(c_reg);
            if (layer == 0) {
                __hip_atomic_store(h0seq + ((size_t)t * 32 + b_u) * 512 + hh_u, hv,
                                   __ATOMIC_RELAXED, __HIP_MEMORY_SCOPE_AGENT);
            } else {
                __hip_atomic_store(out + ((size_t)b_u * 512 + t) * 512 + hh_u, hv,
                                   __ATOMIC_RELAXED, __HIP_MEMORY_SCOPE_AGENT);
            }
            __builtin_amdgcn_fence(__ATOMIC_RELEASE, "agent");
            if (tid == 0)
                __hip_atomic_fetch_add(&cnt[cidx_own + t], 1u,
                                       __ATOMIC_RELEASE, __HIP_MEMORY_SCOPE_AGENT);
        }
        __syncthreads();
    }
}

extern "C" void kernel_launch(void* const* d_in, const int* in_sizes, int n_in,
                              void* d_out, int out_size, void* d_ws, size_t ws_size,
                              hipStream_t stream) {
    const float* inp  = (const float*)d_in[0];
    const float* Wih0 = (const float*)d_in[1];
    const float* Whh0 = (const float*)d_in[2];
    const float* bih0 = (const float*)d_in[3];
    const float* bhh0 = (const float*)d_in[4];
    const float* Wih1 = (const float*)d_in[5];
    const float* Whh1 = (const float*)d_in[6];
    const float* bih1 = (const float*)d_in[7];
    const float* bhh1 = (const float*)d_in[8];
    float* out = (float*)d_out;

    float* h0seq = (float*)d_ws;                                   // 33,554,432 B
    u32* cnt = (u32*)((char*)d_ws + (size_t)512 * 32 * 512 * 4);   // 8,192 B

    (void)hipMemsetAsync((void*)cnt, 0, 2048 * sizeof(u32), stream);

    hipLaunchKernelGGL(lstm_pipe, dim3(512), dim3(256), 0, stream,
                       inp, Wih0, Whh0, bih0, bhh0,
                       Wih1, Whh1, bih1, bhh1,
                       out, h0seq, cnt);
}

// Round 4
// 19944.522 us; speedup vs baseline: 1.2487x; 1.2487x over previous
//
#include <hip/hip_runtime.h>
#include <stddef.h>

#define T_STEPS 512
#define WPITCH 1028   // W tile row pitch (floats): 1024 + 4
#define XPITCH 132    // x/h staging row pitch (floats): 128 + 4
#define RPITCH 20     // reduction scratch pitch (floats): 16 + 4 (16B-aligned rows)

typedef unsigned int u32;

__device__ __forceinline__ float sigmoidf_(float x) {
    return 1.0f / (1.0f + __expf(-x));
}
__device__ __forceinline__ float tanhf_(float x) {
    float ax = fabsf(x);
    float e = __expf(-2.0f * ax);
    float t = (1.0f - e) / (1.0f + e);
    return copysignf(t, x);
}

__device__ __forceinline__ void waitflag(u32* c) {
    if (threadIdx.x == 0) {
        while (__hip_atomic_load(c, __ATOMIC_ACQUIRE, __HIP_MEMORY_SCOPE_AGENT) < 128u)
            __builtin_amdgcn_s_sleep(2);
    }
    // acquire fence: invalidate L1/L2 so subsequent PLAIN loads see producer stores
    __builtin_amdgcn_fence(__ATOMIC_ACQUIRE, "agent");
    __syncthreads();
}

// One phase = 512 k-values, staged as 4 chunks of [16 rows][128 k] in LDS.
// Thread (om,on,ks): 4 batches (4om..4om+3) x 4 gate-rows (4on..4on+3), k-slice ks.
// Per chunk the thread consumes two k-quads at 4*ks and 64+4*ks:
// 8 ds_read_b128 -> 64 FMA (8:1 reuse).
__device__ __forceinline__ void run_phase2(
    const float* __restrict__ src, size_t bstride, int kbase,
    const float (*Wl)[WPITCH], float (*xh)[XPITCH],
    int tid, int ks, int on, int om, float acc[4][4])
{
    const int r0 = tid >> 5, c0 = (tid & 31) << 2;   // staging: rows 0-7 / 8-15
    const int r1 = r0 + 8;
    const float* p0 = src + (size_t)r0 * bstride + c0;
    const float* p1 = src + (size_t)r1 * bstride + c0;
    float4 A = *(const float4*)p0;
    float4 B = *(const float4*)p1;
    const int kq0 = ks << 2;
    const int kq1 = 64 + (ks << 2);
#pragma unroll 1
    for (int ch = 0; ch < 4; ++ch) {
        __syncthreads();                 // previous chunk's consumers done with xh
        *(float4*)&xh[r0][c0] = A;
        *(float4*)&xh[r1][c0] = B;
        __syncthreads();
        if (ch < 3) {                    // prefetch next chunk while computing
            A = *(const float4*)(p0 + ((ch + 1) << 7));
            B = *(const float4*)(p1 + ((ch + 1) << 7));
        }
        const int kW = kbase + (ch << 7);
#pragma unroll
        for (int q = 0; q < 2; ++q) {
            const int kq = q ? kq1 : kq0;
            float4 xq[4], wq[4];
#pragma unroll
            for (int i = 0; i < 4; ++i)
                xq[i] = *(const float4*)&xh[(om << 2) + i][kq];
#pragma unroll
            for (int i = 0; i < 4; ++i)
                wq[i] = *(const float4*)&Wl[(on << 2) + i][kW + kq];
#pragma unroll
            for (int im = 0; im < 4; ++im)
#pragma unroll
                for (int in = 0; in < 4; ++in) {
                    acc[im][in] = fmaf(wq[in].x, xq[im].x, acc[im][in]);
                    acc[im][in] = fmaf(wq[in].y, xq[im].y, acc[im][in]);
                    acc[im][in] = fmaf(wq[in].z, xq[im].z, acc[im][in]);
                    acc[im][in] = fmaf(wq[in].w, xq[im].w, acc[im][in]);
                }
        }
    }
}

// 512 blocks x 256 threads. Co-residency WITHOUT cooperative launch:
// LDS 76,032 B/block -> exactly 2 blocks/CU; grid = 512 = 2 * 256 CUs.
// bid < 256: layer 0; bid >= 256: layer 1.
// Block tile: 16 batches (bg) x 16 gate-rows (hg: 4 hidden x 4 gates), K = 1024.
__global__ void __launch_bounds__(256, 2)
lstm_pipe(const float* __restrict__ inp,                     // [B][T][D]
          const float* __restrict__ Wih0, const float* __restrict__ Whh0,
          const float* __restrict__ bih0, const float* __restrict__ bhh0,
          const float* __restrict__ Wih1, const float* __restrict__ Whh1,
          const float* __restrict__ bih1, const float* __restrict__ bhh1,
          float* __restrict__ out,                           // [B][T][H]
          float* __restrict__ h0seq,                         // [T][B][H] (workspace)
          u32* __restrict__ cnt)                             // [2][2][512] flags
{
    __shared__ float Wl[16][WPITCH];      // 65,792 B
    __shared__ float pool[128 * RPITCH];  // 10,240 B (xh 16x132=2112f overlays; gl overlays)

    const int tid = threadIdx.x;
    const int bid = blockIdx.x;
    const int layer = bid >> 8;
    const int lb = bid & 255;
    const int bg = lb >> 7;
    const int hg = lb & 127;

    const int ks = tid & 15;
    const int on = (tid >> 4) & 3;
    const int om = tid >> 6;

    const float* Wih = layer ? Wih1 : Wih0;
    const float* Whh = layer ? Whh1 : Whh0;
    const float* bih = layer ? bih1 : bih0;
    const float* bhh = layer ? bhh1 : bhh0;

    // ---- stage W (concat [W_ih | W_hh] rows) into LDS once; row n = ph*4+g ----
    for (int r = 0; r < 16; ++r) {
        const int g_r = r & 3, ph_r = r >> 2;
        const int j_r = (g_r << 9) + (hg << 2) + ph_r;
        const int col = tid << 2;
        float4 v;
        if (col < 512) v = *(const float4*)(Wih + (size_t)j_r * 512 + col);
        else           v = *(const float4*)(Whh + (size_t)j_r * 512 + (col - 512));
        *(float4*)&Wl[r][col] = v;
    }

    // ---- output-thread decode (each thread owns ONE of the 256 block outputs) ----
    const int o_half = tid & 127;
    const int om_o = o_half >> 5;
    const int im_o = (o_half >> 4) & 1;
    const int n_o  = o_half & 15;
    const int m_o  = (om_o << 2) + ((tid < 128) ? im_o : (2 + im_o));
    const int g_o  = n_o & 3;
    const int ph_o = n_o >> 2;
    const int j_o  = (g_o << 9) + (hg << 2) + ph_o;
    const float bias = bih[j_o] + bhh[j_o];

    // ---- update-thread mapping (tid < 64) ----
    const int pb_u = tid >> 2, ph_u = tid & 3;
    const int b_u = (bg << 4) + pb_u;
    const int hh_u = (hg << 2) + ph_u;
    float c_reg = 0.0f;

    float (*xh)[XPITCH] = (float (*)[XPITCH])pool;

    const int cidx_own = ((layer << 1) + bg) << 9;  // + t
    const int cidx_l0  = bg << 9;                   // layer0 flags, same bg

    __syncthreads();

    for (int t = 0; t < T_STEPS; ++t) {
        float acc[4][4] = {{0.f,0.f,0.f,0.f},{0.f,0.f,0.f,0.f},
                           {0.f,0.f,0.f,0.f},{0.f,0.f,0.f,0.f}};
        if (layer == 0) {
            // x-part: raw input, no dependency
            run_phase2(inp + ((size_t)(bg * 16) * 512 + t) * 512,
                       (size_t)512 * 512, 0, Wl, xh, tid, ks, on, om, acc);
            if (t > 0) {  // h-part: own layer, step t-1
                waitflag(&cnt[cidx_own + t - 1]);
                run_phase2(h0seq + ((size_t)(t - 1) * 32 + bg * 16) * 512,
                           512, 512, Wl, xh, tid, ks, on, om, acc);
            }
        } else {
            // x-part: layer0 output at step t
            waitflag(&cnt[cidx_l0 + t]);
            run_phase2(h0seq + ((size_t)t * 32 + bg * 16) * 512,
                       512, 0, Wl, xh, tid, ks, on, om, acc);
            if (t > 0) {  // h-part: own hidden state, read back from d_out
                waitflag(&cnt[cidx_own + t - 1]);
                run_phase2(out + ((size_t)(bg * 16) * 512 + (t - 1)) * 512,
                           (size_t)512 * 512, 512, Wl, xh, tid, ks, on, om, acc);
            }
        }

        // ---- 2-pass reduction over the 16 k-slices (scratch overlays xh) ----
        __syncthreads();
#pragma unroll
        for (int im = 0; im < 2; ++im)
#pragma unroll
            for (int in = 0; in < 4; ++in)
                pool[((((om << 1) + im) << 4) | ((on << 2) + in)) * RPITCH + ks] = acc[im][in];
        __syncthreads();
        float gate = 0.f;
        if (tid < 128) {
            const float* row = &pool[tid * RPITCH];
            float4 a = *(const float4*)row;
            float4 b2 = *(const float4*)(row + 4);
            float4 c2 = *(const float4*)(row + 8);
            float4 d2 = *(const float4*)(row + 12);
            gate = (((a.x + a.y) + (a.z + a.w)) + ((b2.x + b2.y) + (b2.z + b2.w)))
                 + (((c2.x + c2.y) + (c2.z + c2.w)) + ((d2.x + d2.y) + (d2.z + d2.w)));
        }
        __syncthreads();
#pragma unroll
        for (int im = 0; im < 2; ++im)
#pragma unroll
            for (int in = 0; in < 4; ++in)
                pool[((((om << 1) + im) << 4) | ((on << 2) + in)) * RPITCH + ks] = acc[im + 2][in];
        __syncthreads();
        if (tid >= 128) {
            const float* row = &pool[(tid - 128) * RPITCH];
            float4 a = *(const float4*)row;
            float4 b2 = *(const float4*)(row + 4);
            float4 c2 = *(const float4*)(row + 8);
            float4 d2 = *(const float4*)(row + 12);
            gate = (((a.x + a.y) + (a.z + a.w)) + ((b2.x + b2.y) + (b2.z + b2.w)))
                 + (((c2.x + c2.y) + (c2.z + c2.w)) + ((d2.x + d2.y) + (d2.z + d2.w)));
        }
        __syncthreads();
        // gate layout for the update wave: gl[(pb*4+ph)][g] overlaid on pool
        pool[(((m_o << 2) + ph_o) << 2) + g_o] = gate + bias;
        __syncthreads();
        if (tid < 64) {  // one thread per (batch, hidden) pair
            const float4 gv = *(const float4*)&pool[tid << 2];
            const float i_ = sigmoidf_(gv.x);
            const float f_ = sigmoidf_(gv.y);
            const float g_ = tanhf_(gv.z);
            const float o_ = sigmoidf_(gv.w);
            c_reg = f_ * c_reg + i_ * g_;
            const float hv = o_ * tanhf_(c_reg);
            if (layer == 0) {
                __hip_atomic_store(h0seq + ((size_t)t * 32 + b_u) * 512 + hh_u, hv,
                                   __ATOMIC_RELAXED, __HIP_MEMORY_SCOPE_AGENT);
            } else {
                __hip_atomic_store(out + ((size_t)b_u * 512 + t) * 512 + hh_u, hv,
                                   __ATOMIC_RELAXED, __HIP_MEMORY_SCOPE_AGENT);
            }
            __builtin_amdgcn_fence(__ATOMIC_RELEASE, "agent");
            if (tid == 0)
                __hip_atomic_fetch_add(&cnt[cidx_own + t], 1u,
                                       __ATOMIC_RELEASE, __HIP_MEMORY_SCOPE_AGENT);
        }
        __syncthreads();
    }
}

extern "C" void kernel_launch(void* const* d_in, const int* in_sizes, int n_in,
                              void* d_out, int out_size, void* d_ws, size_t ws_size,
                              hipStream_t stream) {
    const float* inp  = (const float*)d_in[0];
    const float* Wih0 = (const float*)d_in[1];
    const float* Whh0 = (const float*)d_in[2];
    const float* bih0 = (const float*)d_in[3];
    const float* bhh0 = (const float*)d_in[4];
    const float* Wih1 = (const float*)d_in[5];
    const float* Whh1 = (const float*)d_in[6];
    const float* bih1 = (const float*)d_in[7];
    const float* bhh1 = (const float*)d_in[8];
    float* out = (float*)d_out;

    float* h0seq = (float*)d_ws;                                   // 33,554,432 B
    u32* cnt = (u32*)((char*)d_ws + (size_t)512 * 32 * 512 * 4);   // 8,192 B

    (void)hipMemsetAsync((void*)cnt, 0, 2048 * sizeof(u32), stream);

    hipLaunchKernelGGL(lstm_pipe, dim3(512), dim3(256), 0, stream,
                       inp, Wih0, Whh0, bih0, bhh0,
                       Wih1, Whh1, bih1, bhh1,
                       out, h0seq, cnt);
}